// Round 3
// baseline (1337.528 us; speedup 1.0000x reference)
//
#include <hip/hip_runtime.h>

// InteractionBlock: N=10000, E=320000, C=64, A=4, NB=8, H=8.
// Pipeline:
//   memset cnt -> k_hist -> k_scan (2-barrier shuffle scan)
//   k_build    : p=atomicAdd(cur[dst]); srcs[p]=src; h=(ssp(ee@Wf1/sqrt8))/sqrt8;
//                ehw[p] = {h[8], sh0, sh1[3]}  (CSR-ordered 12-float records)
//   k_node_pre : yq rows [n][u][4]={y0,y1m0..2} (lin1,/8) -> ws; sc (/16) -> out
//   k_agg      : one node per WAVE, no barriers; W_fc2 in regs; float4 y gather;
//                writes raw agg[n][512] to ws
//   k_lin2     : 16 nodes/block, agg staged in LDS, out += (agg @ Wlin2)/64

__global__ __launch_bounds__(256) void k_hist(const int* __restrict__ ei,
                                              int* __restrict__ cnt, int nedges) {
  int e = blockIdx.x * 256 + threadIdx.x;
  if (e < nedges) atomicAdd(&cnt[ei[e]], 1);  // row 0 = dst
}

__global__ __launch_bounds__(1024) void k_scan(const int* __restrict__ cnt,
                                               int* __restrict__ offs,
                                               int* __restrict__ cur,
                                               int nnodes, int nedges) {
  __shared__ int s_wtot[16], s_wpre[16];
  const int tid = threadIdx.x;
  const int lane = tid & 63;
  const int w = tid >> 6;
  int vals[16];
  int tot = 0;
  const int start = tid * 16;
#pragma unroll
  for (int k = 0; k < 16; ++k) {
    int i = start + k;
    int c = (i < nnodes) ? cnt[i] : 0;
    vals[k] = c;
    tot += c;
  }
  int incl = tot;
#pragma unroll
  for (int off = 1; off < 64; off <<= 1) {
    int v = __shfl_up(incl, off, 64);
    if (lane >= off) incl += v;
  }
  if (lane == 63) s_wtot[w] = incl;
  __syncthreads();
  if (tid == 0) {
    int run = 0;
#pragma unroll
    for (int i = 0; i < 16; ++i) { s_wpre[i] = run; run += s_wtot[i]; }
  }
  __syncthreads();
  int run = s_wpre[w] + (incl - tot);
#pragma unroll
  for (int k = 0; k < 16; ++k) {
    int i = start + k;
    if (i < nnodes) {
      offs[i] = run;
      cur[i] = run;
      run += vals[k];
    }
  }
  if (tid == 0) offs[nnodes] = nedges;
}

// scatter + edge-MLP fused: one pass over edges.
__global__ __launch_bounds__(256) void k_build(
    const int* __restrict__ ei, const float* __restrict__ ee,
    const float* __restrict__ ea, const float* __restrict__ Wf1,
    int* __restrict__ cur, int* __restrict__ srcs,
    float* __restrict__ ehw, int nedges) {
  __shared__ float s_w[64];
  const int tid = threadIdx.x;
  if (tid < 64) s_w[tid] = Wf1[tid];
  __syncthreads();
  int e = blockIdx.x * 256 + tid;
  if (e >= nedges) return;
  const int d = ei[e];
  const int s = ei[nedges + e];
  const int p = atomicAdd(&cur[d], 1);
  srcs[p] = s;
  const float4 a = *(const float4*)(ee + (size_t)e * 8);
  const float4 b = *(const float4*)(ee + (size_t)e * 8 + 4);
  float r[8];
  const float is8 = 0.35355339059327379f;  // 1/sqrt(8)
#pragma unroll
  for (int j = 0; j < 8; ++j) {
    float dd = a.x * s_w[0 * 8 + j] + a.y * s_w[1 * 8 + j] + a.z * s_w[2 * 8 + j] +
               a.w * s_w[3 * 8 + j] + b.x * s_w[4 * 8 + j] + b.y * s_w[5 * 8 + j] +
               b.z * s_w[6 * 8 + j] + b.w * s_w[7 * 8 + j];
    dd *= is8;                                        // /sqrt(NB)
    float sp = fmaxf(dd, 0.f) + log1pf(__expf(-fabsf(dd)));
    r[j] = (sp - 0.69314718055994531f) * is8;         // -ln2, fold /sqrt(H)
  }
  const size_t q = (size_t)p * 12;
  *(float4*)(ehw + q) = make_float4(r[0], r[1], r[2], r[3]);
  *(float4*)(ehw + q + 4) = make_float4(r[4], r[5], r[6], r[7]);
  *(float4*)(ehw + q + 8) = *(const float4*)(ea + (size_t)e * 4);  // sh0, sh1
}

// 16 nodes per block (4 per wave), lane = output column v.
__global__ __launch_bounds__(256) void k_node_pre(
    const float* __restrict__ nf, const float* __restrict__ na,
    const float* __restrict__ W10, const float* __restrict__ W11,
    const float* __restrict__ Ws0, const float* __restrict__ Ws1,
    float* __restrict__ yq, float* __restrict__ out, int nnodes) {
  __shared__ float s_nf[16][256];
  __shared__ float s_na[16][4];
  const int tid = threadIdx.x;
  const int lane = tid & 63;
  const int wv = tid >> 6;
  const int base = blockIdx.x * 16;

  for (int i = tid; i < 16 * 256; i += 256) {
    int r = i >> 8, c = i & 255;
    int n = base + r;
    s_nf[r][c] = (n < nnodes) ? nf[(size_t)n * 256 + c] : 0.f;
  }
  if (tid < 64) {
    int r = tid >> 2, c = tid & 3;
    int n = base + r;
    s_na[r][c] = (n < nnodes) ? na[(size_t)n * 4 + c] : 0.f;
  }
  __syncthreads();

  const int r0 = wv * 4;
  const int v = lane;
  float y0a[4] = {0.f, 0.f, 0.f, 0.f};
  float y1a[4][3] = {};
  float sc0a[4] = {0.f, 0.f, 0.f, 0.f};
  float sc1a[4][3] = {};

#pragma unroll 4
  for (int u = 0; u < 64; ++u) {
    float x0r[4], x1r[4][3];
#pragma unroll
    for (int r = 0; r < 4; ++r) {
      x0r[r] = s_nf[r0 + r][u];
#pragma unroll
      for (int m = 0; m < 3; ++m) x1r[r][m] = s_nf[r0 + r][64 + u * 3 + m];
    }
    const float w0 = W10[u * 64 + v];
    const float w1 = W11[u * 64 + v];
#pragma unroll
    for (int r = 0; r < 4; ++r) {
      y0a[r] = fmaf(x0r[r], w0, y0a[r]);
#pragma unroll
      for (int m = 0; m < 3; ++m) y1a[r][m] = fmaf(x1r[r][m], w1, y1a[r][m]);
    }
#pragma unroll
    for (int a = 0; a < 4; ++a) {
      const float ws0 = Ws0[u * 256 + a * 64 + v];
      const float ws1 = Ws1[u * 256 + a * 64 + v];
#pragma unroll
      for (int r = 0; r < 4; ++r) {
        const float nav = s_na[r0 + r][a];
        sc0a[r] = fmaf(x0r[r] * nav, ws0, sc0a[r]);
        const float t = nav * ws1;
#pragma unroll
        for (int m = 0; m < 3; ++m)
          sc1a[r][m] = fmaf(x1r[r][m], t, sc1a[r][m]);
      }
    }
  }

#pragma unroll
  for (int r = 0; r < 4; ++r) {
    const int n = base + r0 + r;
    if (n < nnodes) {
      *(float4*)(yq + ((size_t)n * 64 + v) * 4) =
          make_float4(y0a[r] * 0.125f, y1a[r][0] * 0.125f,
                      y1a[r][1] * 0.125f, y1a[r][2] * 0.125f);  // /sqrt(C)
      out[(size_t)n * 256 + v] = sc0a[r] * 0.0625f;             // /sqrt(C*A)
#pragma unroll
      for (int m = 0; m < 3; ++m)
        out[(size_t)n * 256 + 64 + v * 3 + m] = sc1a[r][m] * 0.0625f;
    }
  }
}

// One node per WAVE; no barriers; writes raw agg[n][512].
__global__ __launch_bounds__(256, 4) void k_agg(
    const float* __restrict__ yq, const float* __restrict__ ehw,
    const int* __restrict__ srcs, const int* __restrict__ offs,
    const float* __restrict__ Wf2, float* __restrict__ agg, int nnodes) {
  const int tid = threadIdx.x;
  const int u = tid & 63;
  const int wv = tid >> 6;
  const int n = blockIdx.x * 4 + wv;
  if (n >= nnodes) return;

  float wreg[32];
#pragma unroll
  for (int j = 0; j < 8; ++j)
#pragma unroll
    for (int q = 0; q < 4; ++q) wreg[j * 4 + q] = Wf2[j * 256 + q * 64 + u];

  float as0 = 0.f, as1 = 0.f;
  float av0[3] = {0.f, 0.f, 0.f};
  float av1[3] = {0.f, 0.f, 0.f};

  const int beg = offs[n], end = offs[n + 1];
#pragma unroll 4
  for (int i = beg; i < end; ++i) {
    const int src = srcs[i];
    const float4 yv = *(const float4*)(yq + ((size_t)src * 64 + u) * 4);
    const float4 h0 = *(const float4*)(ehw + (size_t)i * 12);
    const float4 h1 = *(const float4*)(ehw + (size_t)i * 12 + 4);
    const float4 sh = *(const float4*)(ehw + (size_t)i * 12 + 8);
    const float hv[8] = {h0.x, h0.y, h0.z, h0.w, h1.x, h1.y, h1.z, h1.w};
    float wp[4] = {0.f, 0.f, 0.f, 0.f};
#pragma unroll
    for (int j = 0; j < 8; ++j)
#pragma unroll
      for (int q = 0; q < 4; ++q) wp[q] = fmaf(hv[j], wreg[j * 4 + q], wp[q]);
    const float dot3 = yv.y * sh.y + yv.z * sh.z + yv.w * sh.w;
    as0 = fmaf(wp[0] * yv.x, sh.x, as0);
    as1 = fmaf(wp[3], dot3, as1);
    const float t2 = wp[1] * yv.x;
    av0[0] = fmaf(t2, sh.y, av0[0]);
    av0[1] = fmaf(t2, sh.z, av0[1]);
    av0[2] = fmaf(t2, sh.w, av0[2]);
    const float t3 = wp[2] * sh.x;
    av1[0] = fmaf(t3, yv.y, av1[0]);
    av1[1] = fmaf(t3, yv.z, av1[1]);
    av1[2] = fmaf(t3, yv.w, av1[2]);
  }

  float* ap = agg + (size_t)n * 512;
  ap[u] = as0;
  ap[64 + u] = as1 * 0.57735026918962576f;  // /sqrt(3)
#pragma unroll
  for (int m = 0; m < 3; ++m) {
    ap[128 + m * 64 + u] = av0[m];
    ap[320 + m * 64 + u] = av1[m];
  }
}

// 16 nodes/block (4 per wave); agg rows in LDS; weight reuse 4 nodes x 3 m.
__global__ __launch_bounds__(256) void k_lin2(
    const float* __restrict__ agg, const float* __restrict__ W20,
    const float* __restrict__ W21, float* __restrict__ out, int nnodes) {
  __shared__ float s_x[4][4][512];  // 32 KB
  const int tid = threadIdx.x;
  const int u = tid & 63;
  const int wv = tid >> 6;
  const int nb = blockIdx.x * 16 + wv * 4;

#pragma unroll
  for (int r = 0; r < 4; ++r) {
    const int n = nb + r;
    if (n < nnodes) {
      const float4* srcp = (const float4*)(agg + (size_t)n * 512);
      float4* dst = (float4*)&s_x[wv][r][0];
      dst[u] = srcp[u];
      dst[64 + u] = srcp[64 + u];
    }
  }
  // per-wave private LDS partition: no cross-wave sharing, no barrier needed
  // (compiler inserts lgkmcnt waits for same-wave RAW).

  float o0[4] = {0.f, 0.f, 0.f, 0.f};
  float o1[4][3] = {};

  for (int up = 0; up < 128; up += 4) {
    const float w0_ = W20[(up + 0) * 64 + u];
    const float w1_ = W20[(up + 1) * 64 + u];
    const float w2_ = W20[(up + 2) * 64 + u];
    const float w3_ = W20[(up + 3) * 64 + u];
#pragma unroll
    for (int r = 0; r < 4; ++r) {
      const float4 a = *(const float4*)&s_x[wv][r][up];
      o0[r] = fmaf(a.x, w0_, o0[r]);
      o0[r] = fmaf(a.y, w1_, o0[r]);
      o0[r] = fmaf(a.z, w2_, o0[r]);
      o0[r] = fmaf(a.w, w3_, o0[r]);
    }
  }
  for (int up = 0; up < 64; up += 4) {
    const float w0_ = W21[(up + 0) * 64 + u];
    const float w1_ = W21[(up + 1) * 64 + u];
    const float w2_ = W21[(up + 2) * 64 + u];
    const float w3_ = W21[(up + 3) * 64 + u];
#pragma unroll
    for (int r = 0; r < 4; ++r)
#pragma unroll
      for (int m = 0; m < 3; ++m) {
        const float4 a = *(const float4*)&s_x[wv][r][128 + m * 64 + up];
        o1[r][m] = fmaf(a.x, w0_, o1[r][m]);
        o1[r][m] = fmaf(a.y, w1_, o1[r][m]);
        o1[r][m] = fmaf(a.z, w2_, o1[r][m]);
        o1[r][m] = fmaf(a.w, w3_, o1[r][m]);
      }
  }
  for (int up = 0; up < 64; up += 4) {
    const float w0_ = W21[(64 + up + 0) * 64 + u];
    const float w1_ = W21[(64 + up + 1) * 64 + u];
    const float w2_ = W21[(64 + up + 2) * 64 + u];
    const float w3_ = W21[(64 + up + 3) * 64 + u];
#pragma unroll
    for (int r = 0; r < 4; ++r)
#pragma unroll
      for (int m = 0; m < 3; ++m) {
        const float4 a = *(const float4*)&s_x[wv][r][320 + m * 64 + up];
        o1[r][m] = fmaf(a.x, w0_, o1[r][m]);
        o1[r][m] = fmaf(a.y, w1_, o1[r][m]);
        o1[r][m] = fmaf(a.z, w2_, o1[r][m]);
        o1[r][m] = fmaf(a.w, w3_, o1[r][m]);
      }
  }

  const float scl = 1.f / 64.f;  // 1/sqrt(32) * 1/sqrt(128)
#pragma unroll
  for (int r = 0; r < 4; ++r) {
    const int n = nb + r;
    if (n < nnodes) {
      out[(size_t)n * 256 + u] += o0[r] * scl;
#pragma unroll
      for (int m = 0; m < 3; ++m)
        out[(size_t)n * 256 + 64 + u * 3 + m] += o1[r][m] * scl;
    }
  }
}

extern "C" void kernel_launch(void* const* d_in, const int* in_sizes, int n_in,
                              void* d_out, int out_size, void* d_ws, size_t ws_size,
                              hipStream_t stream) {
  const float* nf = (const float*)d_in[0];
  const float* na = (const float*)d_in[1];
  const float* ea = (const float*)d_in[2];
  const float* ee = (const float*)d_in[3];
  const int* ei = (const int*)d_in[4];
  const float* W10 = (const float*)d_in[5];
  const float* W11 = (const float*)d_in[6];
  const float* Wf1 = (const float*)d_in[7];
  const float* Wf2 = (const float*)d_in[8];
  const float* W20 = (const float*)d_in[9];
  const float* W21 = (const float*)d_in[10];
  const float* Ws0 = (const float*)d_in[11];
  const float* Ws1 = (const float*)d_in[12];
  float* out = (float*)d_out;

  const int N = in_sizes[1] / 4;  // node_attrs is N x 4
  const int E = in_sizes[2] / 4;  // edge_attrs is E x 4

  char* w = (char*)d_ws;
  auto carve = [&](size_t bytes) {
    char* p = w;
    w += (bytes + 255) & ~(size_t)255;
    return p;
  };
  float* yq = (float*)carve((size_t)N * 256 * sizeof(float));   // 10.24 MB
  float* ehw = (float*)carve((size_t)E * 12 * sizeof(float));   // 15.36 MB
  float* agg = (float*)carve((size_t)N * 512 * sizeof(float));  // 20.48 MB
  int* cnt = (int*)carve((size_t)N * sizeof(int));
  int* offs = (int*)carve((size_t)(N + 1) * sizeof(int));
  int* cur = (int*)carve((size_t)N * sizeof(int));
  int* srcs = (int*)carve((size_t)E * sizeof(int));             // 1.28 MB

  hipMemsetAsync(cnt, 0, (size_t)N * sizeof(int), stream);
  const int egrid = (E + 255) / 256;
  k_hist<<<egrid, 256, 0, stream>>>(ei, cnt, E);
  k_scan<<<1, 1024, 0, stream>>>(cnt, offs, cur, N, E);
  k_build<<<egrid, 256, 0, stream>>>(ei, ee, ea, Wf1, cur, srcs, ehw, E);
  k_node_pre<<<(N + 15) / 16, 256, 0, stream>>>(nf, na, W10, W11, Ws0, Ws1, yq, out, N);
  k_agg<<<(N + 3) / 4, 256, 0, stream>>>(yq, ehw, srcs, offs, Wf2, agg, N);
  k_lin2<<<(N + 15) / 16, 256, 0, stream>>>(agg, W20, W21, out, N);
}

// Round 4
// 285.793 us; speedup vs baseline: 4.6801x; 4.6801x over previous
//
#include <hip/hip_runtime.h>

// InteractionBlock: N=10000, E=320000, C=64, A=4, NB=8, H=8.
// Pipeline:
//   memset cnt -> k_hist -> k_scan (2-barrier shuffle scan)
//   k_build    : p=atomicAdd(cur[dst]); srcs[p]=src; h=(ssp(ee@Wf1/sqrt8))/sqrt8;
//                ehw[p] = {h[8], sh0, sh1[3]}  (CSR-ordered 12-float records)
//   k_node_pre : yq rows [n][u][4]={y0,y1m0..2} (lin1,/8) -> ws; sc (/16) -> out
//   k_agg      : one node per WAVE, no barriers; W_fc2 in regs; float4 y gather;
//                writes raw agg[n][512] to ws
//   k_lin2     : 16 nodes/block (4/wave), agg staged in LDS, scalar-broadcast
//                reads + 64-trip K-loop (node_pre-shaped to avoid the round-3
//                256-VGPR spill blowup); out += (agg @ Wlin2)/64

__global__ __launch_bounds__(256) void k_hist(const int* __restrict__ ei,
                                              int* __restrict__ cnt, int nedges) {
  int e = blockIdx.x * 256 + threadIdx.x;
  if (e < nedges) atomicAdd(&cnt[ei[e]], 1);  // row 0 = dst
}

__global__ __launch_bounds__(1024) void k_scan(const int* __restrict__ cnt,
                                               int* __restrict__ offs,
                                               int* __restrict__ cur,
                                               int nnodes, int nedges) {
  __shared__ int s_wtot[16], s_wpre[16];
  const int tid = threadIdx.x;
  const int lane = tid & 63;
  const int w = tid >> 6;
  int vals[16];
  int tot = 0;
  const int start = tid * 16;
#pragma unroll
  for (int k = 0; k < 16; ++k) {
    int i = start + k;
    int c = (i < nnodes) ? cnt[i] : 0;
    vals[k] = c;
    tot += c;
  }
  int incl = tot;
#pragma unroll
  for (int off = 1; off < 64; off <<= 1) {
    int v = __shfl_up(incl, off, 64);
    if (lane >= off) incl += v;
  }
  if (lane == 63) s_wtot[w] = incl;
  __syncthreads();
  if (tid == 0) {
    int run = 0;
#pragma unroll
    for (int i = 0; i < 16; ++i) { s_wpre[i] = run; run += s_wtot[i]; }
  }
  __syncthreads();
  int run = s_wpre[w] + (incl - tot);
#pragma unroll
  for (int k = 0; k < 16; ++k) {
    int i = start + k;
    if (i < nnodes) {
      offs[i] = run;
      cur[i] = run;
      run += vals[k];
    }
  }
  if (tid == 0) offs[nnodes] = nedges;
}

// scatter + edge-MLP fused: one pass over edges.
__global__ __launch_bounds__(256) void k_build(
    const int* __restrict__ ei, const float* __restrict__ ee,
    const float* __restrict__ ea, const float* __restrict__ Wf1,
    int* __restrict__ cur, int* __restrict__ srcs,
    float* __restrict__ ehw, int nedges) {
  __shared__ float s_w[64];
  const int tid = threadIdx.x;
  if (tid < 64) s_w[tid] = Wf1[tid];
  __syncthreads();
  int e = blockIdx.x * 256 + tid;
  if (e >= nedges) return;
  const int d = ei[e];
  const int s = ei[nedges + e];
  const int p = atomicAdd(&cur[d], 1);
  srcs[p] = s;
  const float4 a = *(const float4*)(ee + (size_t)e * 8);
  const float4 b = *(const float4*)(ee + (size_t)e * 8 + 4);
  float r[8];
  const float is8 = 0.35355339059327379f;  // 1/sqrt(8)
#pragma unroll
  for (int j = 0; j < 8; ++j) {
    float dd = a.x * s_w[0 * 8 + j] + a.y * s_w[1 * 8 + j] + a.z * s_w[2 * 8 + j] +
               a.w * s_w[3 * 8 + j] + b.x * s_w[4 * 8 + j] + b.y * s_w[5 * 8 + j] +
               b.z * s_w[6 * 8 + j] + b.w * s_w[7 * 8 + j];
    dd *= is8;                                        // /sqrt(NB)
    float sp = fmaxf(dd, 0.f) + log1pf(__expf(-fabsf(dd)));
    r[j] = (sp - 0.69314718055994531f) * is8;         // -ln2, fold /sqrt(H)
  }
  const size_t q = (size_t)p * 12;
  *(float4*)(ehw + q) = make_float4(r[0], r[1], r[2], r[3]);
  *(float4*)(ehw + q + 4) = make_float4(r[4], r[5], r[6], r[7]);
  *(float4*)(ehw + q + 8) = *(const float4*)(ea + (size_t)e * 4);  // sh0, sh1
}

// 16 nodes per block (4 per wave), lane = output column v.
__global__ __launch_bounds__(256) void k_node_pre(
    const float* __restrict__ nf, const float* __restrict__ na,
    const float* __restrict__ W10, const float* __restrict__ W11,
    const float* __restrict__ Ws0, const float* __restrict__ Ws1,
    float* __restrict__ yq, float* __restrict__ out, int nnodes) {
  __shared__ float s_nf[16][256];
  __shared__ float s_na[16][4];
  const int tid = threadIdx.x;
  const int lane = tid & 63;
  const int wv = tid >> 6;
  const int base = blockIdx.x * 16;

  for (int i = tid; i < 16 * 256; i += 256) {
    int r = i >> 8, c = i & 255;
    int n = base + r;
    s_nf[r][c] = (n < nnodes) ? nf[(size_t)n * 256 + c] : 0.f;
  }
  if (tid < 64) {
    int r = tid >> 2, c = tid & 3;
    int n = base + r;
    s_na[r][c] = (n < nnodes) ? na[(size_t)n * 4 + c] : 0.f;
  }
  __syncthreads();

  const int r0 = wv * 4;
  const int v = lane;
  float y0a[4] = {0.f, 0.f, 0.f, 0.f};
  float y1a[4][3] = {};
  float sc0a[4] = {0.f, 0.f, 0.f, 0.f};
  float sc1a[4][3] = {};

#pragma unroll 4
  for (int u = 0; u < 64; ++u) {
    float x0r[4], x1r[4][3];
#pragma unroll
    for (int r = 0; r < 4; ++r) {
      x0r[r] = s_nf[r0 + r][u];
#pragma unroll
      for (int m = 0; m < 3; ++m) x1r[r][m] = s_nf[r0 + r][64 + u * 3 + m];
    }
    const float w0 = W10[u * 64 + v];
    const float w1 = W11[u * 64 + v];
#pragma unroll
    for (int r = 0; r < 4; ++r) {
      y0a[r] = fmaf(x0r[r], w0, y0a[r]);
#pragma unroll
      for (int m = 0; m < 3; ++m) y1a[r][m] = fmaf(x1r[r][m], w1, y1a[r][m]);
    }
#pragma unroll
    for (int a = 0; a < 4; ++a) {
      const float ws0 = Ws0[u * 256 + a * 64 + v];
      const float ws1 = Ws1[u * 256 + a * 64 + v];
#pragma unroll
      for (int r = 0; r < 4; ++r) {
        const float nav = s_na[r0 + r][a];
        sc0a[r] = fmaf(x0r[r] * nav, ws0, sc0a[r]);
        const float t = nav * ws1;
#pragma unroll
        for (int m = 0; m < 3; ++m)
          sc1a[r][m] = fmaf(x1r[r][m], t, sc1a[r][m]);
      }
    }
  }

#pragma unroll
  for (int r = 0; r < 4; ++r) {
    const int n = base + r0 + r;
    if (n < nnodes) {
      *(float4*)(yq + ((size_t)n * 64 + v) * 4) =
          make_float4(y0a[r] * 0.125f, y1a[r][0] * 0.125f,
                      y1a[r][1] * 0.125f, y1a[r][2] * 0.125f);  // /sqrt(C)
      out[(size_t)n * 256 + v] = sc0a[r] * 0.0625f;             // /sqrt(C*A)
#pragma unroll
      for (int m = 0; m < 3; ++m)
        out[(size_t)n * 256 + 64 + v * 3 + m] = sc1a[r][m] * 0.0625f;
    }
  }
}

// One node per WAVE; no barriers; writes raw agg[n][512].
__global__ __launch_bounds__(256, 4) void k_agg(
    const float* __restrict__ yq, const float* __restrict__ ehw,
    const int* __restrict__ srcs, const int* __restrict__ offs,
    const float* __restrict__ Wf2, float* __restrict__ agg, int nnodes) {
  const int tid = threadIdx.x;
  const int u = tid & 63;
  const int wv = tid >> 6;
  const int n = blockIdx.x * 4 + wv;
  if (n >= nnodes) return;

  float wreg[32];
#pragma unroll
  for (int j = 0; j < 8; ++j)
#pragma unroll
    for (int q = 0; q < 4; ++q) wreg[j * 4 + q] = Wf2[j * 256 + q * 64 + u];

  float as0 = 0.f, as1 = 0.f;
  float av0[3] = {0.f, 0.f, 0.f};
  float av1[3] = {0.f, 0.f, 0.f};

  const int beg = offs[n], end = offs[n + 1];
#pragma unroll 4
  for (int i = beg; i < end; ++i) {
    const int src = srcs[i];
    const float4 yv = *(const float4*)(yq + ((size_t)src * 64 + u) * 4);
    const float4 h0 = *(const float4*)(ehw + (size_t)i * 12);
    const float4 h1 = *(const float4*)(ehw + (size_t)i * 12 + 4);
    const float4 sh = *(const float4*)(ehw + (size_t)i * 12 + 8);
    const float hv[8] = {h0.x, h0.y, h0.z, h0.w, h1.x, h1.y, h1.z, h1.w};
    float wp[4] = {0.f, 0.f, 0.f, 0.f};
#pragma unroll
    for (int j = 0; j < 8; ++j)
#pragma unroll
      for (int q = 0; q < 4; ++q) wp[q] = fmaf(hv[j], wreg[j * 4 + q], wp[q]);
    const float dot3 = yv.y * sh.y + yv.z * sh.z + yv.w * sh.w;
    as0 = fmaf(wp[0] * yv.x, sh.x, as0);
    as1 = fmaf(wp[3], dot3, as1);
    const float t2 = wp[1] * yv.x;
    av0[0] = fmaf(t2, sh.y, av0[0]);
    av0[1] = fmaf(t2, sh.z, av0[1]);
    av0[2] = fmaf(t2, sh.w, av0[2]);
    const float t3 = wp[2] * sh.x;
    av1[0] = fmaf(t3, yv.y, av1[0]);
    av1[1] = fmaf(t3, yv.z, av1[1]);
    av1[2] = fmaf(t3, yv.w, av1[2]);
  }

  float* ap = agg + (size_t)n * 512;
  ap[u] = as0;
  ap[64 + u] = as1 * 0.57735026918962576f;  // /sqrt(3)
#pragma unroll
  for (int m = 0; m < 3; ++m) {
    ap[128 + m * 64 + u] = av0[m];
    ap[320 + m * 64 + u] = av1[m];
  }
}

// 16 nodes/block (4 per wave); per-wave private LDS slice; scalar broadcast
// reads; single 64-trip K-loop with bounded unroll (anti-spill, see round 3).
__global__ __launch_bounds__(256, 4) void k_lin2(
    const float* __restrict__ agg, const float* __restrict__ W20,
    const float* __restrict__ W21, float* __restrict__ out, int nnodes) {
  __shared__ float s_x[4][4][512];  // 32 KB
  const int tid = threadIdx.x;
  const int u = tid & 63;
  const int wv = tid >> 6;
  const int nb = blockIdx.x * 16 + wv * 4;

#pragma unroll
  for (int r = 0; r < 4; ++r) {
    const int n = nb + r;
    if (n < nnodes) {
      const float4* srcp = (const float4*)(agg + (size_t)n * 512);
      float4* dst = (float4*)&s_x[wv][r][0];
      dst[u] = srcp[u];
      dst[64 + u] = srcp[64 + u];
    }
  }
  // per-wave private LDS slice: same-wave RAW only, no barrier needed.

  float o0[4] = {0.f, 0.f, 0.f, 0.f};
  float o1[4][3] = {};

#pragma unroll 2
  for (int up = 0; up < 64; ++up) {
    const float w20a = W20[up * 64 + u];
    const float w20b = W20[(64 + up) * 64 + u];
    const float w21a = W21[up * 64 + u];
    const float w21b = W21[(64 + up) * 64 + u];
#pragma unroll
    for (int r = 0; r < 4; ++r) {
      o0[r] = fmaf(s_x[wv][r][up], w20a, o0[r]);
      o0[r] = fmaf(s_x[wv][r][64 + up], w20b, o0[r]);
#pragma unroll
      for (int m = 0; m < 3; ++m) {
        o1[r][m] = fmaf(s_x[wv][r][128 + m * 64 + up], w21a, o1[r][m]);
        o1[r][m] = fmaf(s_x[wv][r][320 + m * 64 + up], w21b, o1[r][m]);
      }
    }
  }

  const float scl = 1.f / 64.f;  // 1/sqrt(32) * 1/sqrt(128)
#pragma unroll
  for (int r = 0; r < 4; ++r) {
    const int n = nb + r;
    if (n < nnodes) {
      out[(size_t)n * 256 + u] += o0[r] * scl;
#pragma unroll
      for (int m = 0; m < 3; ++m)
        out[(size_t)n * 256 + 64 + u * 3 + m] += o1[r][m] * scl;
    }
  }
}

extern "C" void kernel_launch(void* const* d_in, const int* in_sizes, int n_in,
                              void* d_out, int out_size, void* d_ws, size_t ws_size,
                              hipStream_t stream) {
  const float* nf = (const float*)d_in[0];
  const float* na = (const float*)d_in[1];
  const float* ea = (const float*)d_in[2];
  const float* ee = (const float*)d_in[3];
  const int* ei = (const int*)d_in[4];
  const float* W10 = (const float*)d_in[5];
  const float* W11 = (const float*)d_in[6];
  const float* Wf1 = (const float*)d_in[7];
  const float* Wf2 = (const float*)d_in[8];
  const float* W20 = (const float*)d_in[9];
  const float* W21 = (const float*)d_in[10];
  const float* Ws0 = (const float*)d_in[11];
  const float* Ws1 = (const float*)d_in[12];
  float* out = (float*)d_out;

  const int N = in_sizes[1] / 4;  // node_attrs is N x 4
  const int E = in_sizes[2] / 4;  // edge_attrs is E x 4

  char* w = (char*)d_ws;
  auto carve = [&](size_t bytes) {
    char* p = w;
    w += (bytes + 255) & ~(size_t)255;
    return p;
  };
  float* yq = (float*)carve((size_t)N * 256 * sizeof(float));   // 10.24 MB
  float* ehw = (float*)carve((size_t)E * 12 * sizeof(float));   // 15.36 MB
  float* agg = (float*)carve((size_t)N * 512 * sizeof(float));  // 20.48 MB
  int* cnt = (int*)carve((size_t)N * sizeof(int));
  int* offs = (int*)carve((size_t)(N + 1) * sizeof(int));
  int* cur = (int*)carve((size_t)N * sizeof(int));
  int* srcs = (int*)carve((size_t)E * sizeof(int));             // 1.28 MB

  hipMemsetAsync(cnt, 0, (size_t)N * sizeof(int), stream);
  const int egrid = (E + 255) / 256;
  k_hist<<<egrid, 256, 0, stream>>>(ei, cnt, E);
  k_scan<<<1, 1024, 0, stream>>>(cnt, offs, cur, N, E);
  k_build<<<egrid, 256, 0, stream>>>(ei, ee, ea, Wf1, cur, srcs, ehw, E);
  k_node_pre<<<(N + 15) / 16, 256, 0, stream>>>(nf, na, W10, W11, Ws0, Ws1, yq, out, N);
  k_agg<<<(N + 3) / 4, 256, 0, stream>>>(yq, ehw, srcs, offs, Wf2, agg, N);
  k_lin2<<<(N + 15) / 16, 256, 0, stream>>>(agg, W20, W21, out, N);
}